// Round 9
// baseline (74.038 us; speedup 1.0000x reference)
//
#include <hip/hip_runtime.h>
#include <math.h>

#define N 4096
#define D 512
#define NCLASS 31

typedef unsigned short u16;
typedef unsigned int u32;
typedef short bf16x8 __attribute__((ext_vector_type(8)));
typedef float f32x4 __attribute__((ext_vector_type(4)));

__device__ __forceinline__ u32 f2bf(float x) {
    u32 u = __float_as_uint(x);
    return (u + 0x7FFFu + ((u >> 16) & 1u)) >> 16;  // RNE bf16 (no inf/nan in data)
}
__device__ __forceinline__ float bf2f(u32 h) {
    return __uint_as_float(h << 16);
}

__device__ __forceinline__ void gll16(const void* g, void* l) {
    __builtin_amdgcn_global_load_lds(
        (const __attribute__((address_space(1))) u32*)g,
        (__attribute__((address_space(3))) u32*)l, 16, 0, 0);
}

// ---------------- ws layout (float units) ----------------
constexpr size_t HI_FLOATS  = (size_t)N * D / 2;        // bf16 copy of X
constexpr size_t OFF_SQH    = HI_FLOATS;                // N
constexpr size_t OFF_DENP   = OFF_SQH + N;              // 32*N slabs
constexpr size_t OFF_SP     = OFF_DENP + 32 * (size_t)N;// 32*N slabs
constexpr size_t OFF_COLSUM = OFF_SP + 32 * (size_t)N;  // 512
constexpr size_t OFF_SUMSQ  = OFF_COLSUM + 512;         // 1
constexpr size_t OFF_LS     = OFF_SUMSQ + 1;            // 1 loss-sum
constexpr size_t OFF_VS     = OFF_LS + 1;               // 1 valid-sum
constexpr size_t OFF_TK     = OFF_VS + 1;               // 1 ticket (int)
constexpr size_t ZERO_FLOATS = 512 + 4;                 // colsum..ticket
constexpr size_t WS_NEED    = (OFF_TK + 64) * 4;        // ~5.3 MB

// ============ prep: fp32->bf16 + colsum/sumsq atomics + rowsq ============
// 256 blocks x 256 threads, 16 rows each (proven R2/R3/R8 pattern).
__global__ __launch_bounds__(256) void prep_kernel(const float* __restrict__ X,
                                                   u16* __restrict__ hi,
                                                   float* __restrict__ sqh,
                                                   float* __restrict__ colsum,
                                                   float* __restrict__ sumsq) {
    const int t = threadIdx.x;
    const int r0 = blockIdx.x * 16;
    float cs0 = 0.f, cs1 = 0.f, ss = 0.f;
    #pragma unroll 4
    for (int r = r0; r < r0 + 16; r++) {
        float2 v = *(const float2*)(X + (size_t)r * D + t * 2);
        u32 h0 = f2bf(v.x), h1 = f2bf(v.y);
        *(u32*)(hi + (size_t)r * D + t * 2) = h0 | (h1 << 16);
        float q0 = bf2f(h0), q1 = bf2f(h1);
        cs0 += q0; cs1 += q1;
        ss += q0 * q0 + q1 * q1;
    }
    atomicAdd(&colsum[t * 2], cs0);
    atomicAdd(&colsum[t * 2 + 1], cs1);
    __shared__ float red[4];
    const int ln = t & 63, wv = t >> 6;
    #pragma unroll
    for (int m = 32; m; m >>= 1) ss += __shfl_xor(ss, m);
    if (ln == 0) red[wv] = ss;
    __syncthreads();
    if (t == 0) atomicAdd(sumsq, red[0] + red[1] + red[2] + red[3]);
    // per-row sq-norm from hi (written by this block, visible post-barrier)
    #pragma unroll
    for (int i = 0; i < 4; i++) {
        int r = r0 + wv * 4 + i;
        bf16x8 v = *(const bf16x8*)(hi + (size_t)r * D + ln * 8);
        float s = 0.f;
        #pragma unroll
        for (int j = 0; j < 8; j++) { float f = bf2f((u16)(unsigned short)v[j]); s += f * f; }
        #pragma unroll
        for (int m = 32; m; m >>= 1) s += __shfl_xor(s, m);
        if (ln == 0) sqh[r] = s;
    }
}

// ============ symmetric fused MFMA Gram + RBF + contrastive stats ============
// Upper-triangle 528 blocks, 128x128 tile, 4 waves (2x2 quadrants), 16x16x32
// bf16 MFMA, BK=32 (16 K-steps), 2-buffer LDS = 32KB -> 4 blocks/CU capacity:
// ALL 528 blocks co-resident in ONE round (kills the R8 tail: 2/CU capacity
// made 528 = 512 + 16 => two rounds => ~2x wall).
// Staging: global_load_lds, pre-swizzled global chunk c_g = (l&3)^(row&3);
// each instr = 16 rows x 64B, zero staging VGPRs. Fragment ds_read applies
// the same involution phys = (l>>4)^(l&3): verified 8-cycle floor (no
// conflicts). Counted vmcnt(4) mid-loop (never 0), 2 raw barriers/step.
__global__ __launch_bounds__(256, 4) void gemm_mfma_kernel(const u16* __restrict__ hi,
                                                           const int* __restrict__ lab,
                                                           const float* __restrict__ sqh,
                                                           const float* __restrict__ colsum,
                                                           const float* __restrict__ sumsq,
                                                           float* __restrict__ denP,
                                                           float* __restrict__ SP) {
    __shared__ u16 As[2][128 * 32];
    __shared__ u16 Bs[2][128 * 32];
    __shared__ float bwS;
    const int tid = threadIdx.x;
    const int w = tid >> 6, l = tid & 63;

    // bijective XCD swizzle (528 = 8*66) then triangular decode (by <= bx)
    const int bid = blockIdx.x;
    int b = (bid & 7) * 66 + (bid >> 3);
    int by = 0;
    while (b >= 32 - by) { b -= 32 - by; ++by; }
    const int bx = by + b;
    const bool offdiag = (bx != by);
    const int rowBase = by * 128, colBase = bx * 128;
    const int wr = w >> 1, wc = w & 1;

    // pre-swizzled per-lane staging address:
    // slot = i*256 + tid -> row = i*64 + w*16 + (l>>2), phys chunk = l&3,
    // global logical chunk = (l&3) ^ (row&3) = (l&3) ^ ((l>>2)&3)
    const int srow = w * 16 + (l >> 2);
    const int schunk = (l & 3) ^ ((l >> 2) & 3);
    const u16* pA = hi + (size_t)(rowBase + srow) * D + schunk * 8;
    const u16* pB = hi + (size_t)(colBase + srow) * D + schunk * 8;

#define STAGE(BUF, K0) {                                                        \
    _Pragma("unroll")                                                           \
    for (int i = 0; i < 2; i++)                                                 \
        gll16(pA + (size_t)(i * 64) * D + (K0), &As[BUF][(i * 256 + w * 64) * 8]); \
    _Pragma("unroll")                                                           \
    for (int i = 0; i < 2; i++)                                                 \
        gll16(pB + (size_t)(i * 64) * D + (K0), &Bs[BUF][(i * 256 + w * 64) * 8]); }

    STAGE(0, 0)

    // bandwidth preamble (wave 0 only; 2KB colsum; overlaps stage-0 flight)
    if (tid < 64) {
        float s = 0.f;
        for (int k = tid; k < D; k += 64) { float v = colsum[k]; s += v * v; }
        #pragma unroll
        for (int m = 32; m; m >>= 1) s += __shfl_xor(s, m);
        if (tid == 0) {
            double total = 2.0 * (double)N * (double)(*sumsq) - 2.0 * (double)s;
            bwS = (float)(total / ((double)N * (double)N - (double)N) * 0.25);
        }
    }

    f32x4 zero = {0.f, 0.f, 0.f, 0.f};
    f32x4 acc[4][4];
    #pragma unroll
    for (int i = 0; i < 4; i++)
        #pragma unroll
        for (int j = 0; j < 4; j++) acc[i][j] = zero;

    // fragment read: row = q*64 + m*16 + (l&15), logical c = l>>4,
    // phys = c ^ (row&3) = (l>>4) ^ (l&3)  (row&3 == (l&15)&3 == l&3)
    const int px = ((l >> 4) ^ (l & 3)) * 8;
    const int abase = (wr * 64 + (l & 15)) * 32 + px;
    const int bbase = (wc * 64 + (l & 15)) * 32 + px;

#define KSTEP(T, CNT) {                                                         \
    if ((T) < 15) STAGE(((T) + 1) & 1, ((T) + 1) * 32)                          \
    asm volatile("s_waitcnt vmcnt(" CNT ")\n\ts_barrier" ::: "memory");         \
    bf16x8 af[4], bfr[4];                                                       \
    _Pragma("unroll")                                                           \
    for (int m = 0; m < 4; m++)                                                 \
        af[m] = *(const bf16x8*)&As[(T) & 1][abase + m * 16 * 32];              \
    _Pragma("unroll")                                                           \
    for (int n = 0; n < 4; n++)                                                 \
        bfr[n] = *(const bf16x8*)&Bs[(T) & 1][bbase + n * 16 * 32];             \
    _Pragma("unroll")                                                           \
    for (int m = 0; m < 4; m++)                                                 \
        _Pragma("unroll")                                                       \
        for (int n = 0; n < 4; n++)                                             \
            acc[m][n] = __builtin_amdgcn_mfma_f32_16x16x32_bf16(                \
                af[m], bfr[n], acc[m][n], 0, 0, 0);                             \
    asm volatile("s_barrier" ::: "memory"); }

    KSTEP(0, "4")  KSTEP(1, "4")  KSTEP(2, "4")  KSTEP(3, "4")
    KSTEP(4, "4")  KSTEP(5, "4")  KSTEP(6, "4")  KSTEP(7, "4")
    KSTEP(8, "4")  KSTEP(9, "4")  KSTEP(10, "4") KSTEP(11, "4")
    KSTEP(12, "4") KSTEP(13, "4") KSTEP(14, "4") KSTEP(15, "0")
#undef KSTEP
#undef STAGE

    // ---- epilogue: L2 -> 5-kernel sum via u^{1,2,4,8,16} -> row+col partials ----
    const float bw = bwS;
    const float c4 = 1.0f / (16.0f * bw);
    constexpr float INV_T = 1.0f / 0.35f;  // 1/(TEMPERATURE*KERNEL_NUM)

    const int col0 = colBase + wc * 64 + (l & 15);
    float sqC[4]; int labC[4];
    #pragma unroll
    for (int n = 0; n < 4; n++) { sqC[n] = sqh[col0 + n * 16]; labC[n] = lab[col0 + n * 16]; }
    const int rbase = rowBase + wr * 64 + (l >> 4) * 4;

    float dCol[4] = {0.f, 0.f, 0.f, 0.f};
    float sCol[4] = {0.f, 0.f, 0.f, 0.f};

    // LDS scratch over As[0] (all K-loop reads complete past final barrier)
    float* fDr = (float*)&As[0][0];   // [2(wc)][128] row den partials
    float* fSr = fDr + 256;
    float* fDc = fDr + 512;           // [2(wr)][128] col den partials
    float* fSc = fDr + 768;

    #pragma unroll
    for (int m = 0; m < 4; m++) {
        #pragma unroll
        for (int rg = 0; rg < 4; rg++) {
            const int r = rbase + m * 16 + rg;
            const float sqR = sqh[r];
            const int labR = lab[r];
            float dA = 0.f, sA2 = 0.f;
            #pragma unroll
            for (int n = 0; n < 4; n++) {
                float gv = acc[m][n][rg];
                float L2 = fmaxf(sqR + sqC[n] - 2.0f * gv, 0.0f);
                float u = __expf(-L2 * c4);
                float u2 = u * u, u4 = u2 * u2, u8 = u4 * u4, u16v = u8 * u8;
                float k5 = ((((u + u2) + u4) + u8) + u16v) - 5.0f;  // kern-5 (diag->0)
                float e = __expf(k5 * INV_T);
                dA += e;
                dCol[n] += e;
                if (labR == labC[n]) { sA2 += k5; sCol[n] += k5; }
            }
            #pragma unroll
            for (int mm = 1; mm <= 8; mm <<= 1) {
                dA += __shfl_xor(dA, mm);
                sA2 += __shfl_xor(sA2, mm);
            }
            if ((l & 15) == 0) {
                int rloc = wr * 64 + m * 16 + (l >> 4) * 4 + rg;
                fDr[wc * 128 + rloc] = dA;
                fSr[wc * 128 + rloc] = sA2;
            }
        }
    }
    #pragma unroll
    for (int n = 0; n < 4; n++) {
        float d = dCol[n], s = sCol[n];
        d += __shfl_xor(d, 16); d += __shfl_xor(d, 32);
        s += __shfl_xor(s, 16); s += __shfl_xor(s, 32);
        if (l < 16) {
            int cloc = wc * 64 + n * 16 + l;
            fDc[wr * 128 + cloc] = d;
            fSc[wr * 128 + cloc] = s;
        }
    }
    __syncthreads();
    if (tid < 128) {
        int r = rowBase + tid;
        denP[(size_t)bx * N + r] = fDr[tid] + fDr[128 + tid];
        SP[(size_t)bx * N + r]   = fSr[tid] + fSr[128 + tid];
    } else if (offdiag) {
        int t2 = tid - 128;
        int c = colBase + t2;
        denP[(size_t)by * N + c] = fDc[t2] + fDc[tid];
        SP[(size_t)by * N + c]   = fSc[t2] + fSc[tid];
    }
}

// ============ finalize (fused): per-row loss -> block sums -> ticket ============
__global__ __launch_bounds__(256) void fin_kernel(const float* __restrict__ denP,
                                                  const float* __restrict__ SP,
                                                  const int* __restrict__ lab,
                                                  float* __restrict__ lsSum,
                                                  float* __restrict__ vsSum,
                                                  int* __restrict__ ticket,
                                                  float* __restrict__ out) {
    __shared__ int h[NCLASS];
    const int tid = threadIdx.x;
    if (tid < NCLASS) h[tid] = 0;
    __syncthreads();
    for (int i = tid; i < N; i += 256) atomicAdd(&h[lab[i]], 1);  // LDS atomics
    __syncthreads();
    const int r = blockIdx.x * 256 + tid;
    float dsum = -1.0f, ssum = 0.0f;  // -1: exact diagonal exp-term removal
    #pragma unroll 8
    for (int k = 0; k < 32; k++) {
        dsum += denP[(size_t)k * N + r];
        ssum += SP[(size_t)k * N + r];
    }
    constexpr float INV_T = 1.0f / 0.35f;
    int P = h[lab[r]] - 1;
    float loss = 0.f, val = 0.f;
    if (P > 0) {
        float fl = (float)P;
        loss = -(ssum * INV_T - fl * logf(dsum)) / fl;
        val = 1.f;
    }
    // block reduction
    __shared__ float s1[4], s2[4];
    const int ln = tid & 63, wv = tid >> 6;
    #pragma unroll
    for (int m = 32; m; m >>= 1) {
        loss += __shfl_xor(loss, m);
        val  += __shfl_xor(val, m);
    }
    if (ln == 0) { s1[wv] = loss; s2[wv] = val; }
    __syncthreads();
    if (tid == 0) {
        atomicAdd(lsSum, s1[0] + s1[1] + s1[2] + s1[3]);
        atomicAdd(vsSum, s2[0] + s2[1] + s2[2] + s2[3]);
        __threadfence();
        if (atomicAdd(ticket, 1) == (int)gridDim.x - 1) {
            float a = atomicAdd(lsSum, 0.0f);   // coherent read
            float v = atomicAdd(vsSum, 0.0f);
            out[0] = a / fmaxf(v, 1.0f);
        }
    }
}

// ======================================================================
// ================= fallback fp32 path (round-1, known-good) ===========
// ======================================================================
constexpr int WS_FLOATS_OLD = 12802 + 32;

__global__ __launch_bounds__(256) void rowsq_kernel(const float* __restrict__ X,
                                                    float* __restrict__ sq,
                                                    float* __restrict__ sumsq) {
    int wave = threadIdx.x >> 6;
    int lane = threadIdx.x & 63;
    int row = blockIdx.x * 4 + wave;
    const float4* p = (const float4*)(X + (size_t)row * D);
    float4 v0 = p[lane * 2];
    float4 v1 = p[lane * 2 + 1];
    float s = v0.x * v0.x + v0.y * v0.y + v0.z * v0.z + v0.w * v0.w
            + v1.x * v1.x + v1.y * v1.y + v1.z * v1.z + v1.w * v1.w;
    #pragma unroll
    for (int m = 32; m; m >>= 1) s += __shfl_xor(s, m);
    if (lane == 0) { sq[row] = s; atomicAdd(sumsq, s); }
}

__global__ __launch_bounds__(256) void colsum_kernel(const float* __restrict__ X,
                                                     float* __restrict__ colsum) {
    int c0 = threadIdx.x;
    int c1 = threadIdx.x + 256;
    int r0 = blockIdx.x * 64;
    float s0 = 0.f, s1 = 0.f;
    for (int r = r0; r < r0 + 64; r++) {
        s0 += X[(size_t)r * D + c0];
        s1 += X[(size_t)r * D + c1];
    }
    atomicAdd(&colsum[c0], s0);
    atomicAdd(&colsum[c1], s1);
}

__global__ __launch_bounds__(256) void hist_kernel(const int* __restrict__ lab,
                                                   int* __restrict__ cnt) {
    int i = blockIdx.x * 256 + threadIdx.x;
    if (i < N) atomicAdd(&cnt[lab[i]], 1);
}

__global__ __launch_bounds__(64) void bw_kernel(const float* __restrict__ colsum,
                                                const float* __restrict__ sumsq,
                                                float* __restrict__ bw) {
    int lane = threadIdx.x;
    float s = 0.f;
    for (int k = lane; k < D; k += 64) { float v = colsum[k]; s += v * v; }
    #pragma unroll
    for (int m = 32; m; m >>= 1) s += __shfl_xor(s, m);
    if (lane == 0) {
        double total = 2.0 * (double)N * (double)(*sumsq) - 2.0 * (double)s;
        double b = total / ((double)N * (double)N - (double)N);
        *bw = (float)(b / 4.0);
    }
}

constexpr int BM = 128, BN = 128, BK = 16;

__global__ __launch_bounds__(256) void gemm_fused_kernel(const float* __restrict__ X,
                                                         const int* __restrict__ lab,
                                                         const float* __restrict__ sq,
                                                         const float* __restrict__ bwp,
                                                         float* __restrict__ denom,
                                                         float* __restrict__ Ssum) {
    __shared__ float As[BK][BM];
    __shared__ float Bs[BK][BN];
    const int tid = threadIdx.x;
    const int nbx = N / BN;
    const int bx = blockIdx.x % nbx;
    const int by = blockIdx.x / nbx;
    const int rowBase = by * BM, colBase = bx * BN;
    const int lr = tid >> 1;
    const int lc = (tid & 1) * 8;
    const float* Ap = X + (size_t)(rowBase + lr) * D + lc;
    const float* Bp = X + (size_t)(colBase + lr) * D + lc;
    const int ty = tid >> 4, tx = tid & 15;

    float acc[8][8];
    #pragma unroll
    for (int i = 0; i < 8; i++)
        #pragma unroll
        for (int j = 0; j < 8; j++) acc[i][j] = 0.f;

    for (int k0 = 0; k0 < D; k0 += BK) {
        float4 a0 = *(const float4*)(Ap + k0);
        float4 a1 = *(const float4*)(Ap + k0 + 4);
        float4 b0 = *(const float4*)(Bp + k0);
        float4 b1 = *(const float4*)(Bp + k0 + 4);
        __syncthreads();
        As[lc + 0][lr] = a0.x; As[lc + 1][lr] = a0.y;
        As[lc + 2][lr] = a0.z; As[lc + 3][lr] = a0.w;
        As[lc + 4][lr] = a1.x; As[lc + 5][lr] = a1.y;
        As[lc + 6][lr] = a1.z; As[lc + 7][lr] = a1.w;
        Bs[lc + 0][lr] = b0.x; Bs[lc + 1][lr] = b0.y;
        Bs[lc + 2][lr] = b0.z; Bs[lc + 3][lr] = b0.w;
        Bs[lc + 4][lr] = b1.x; Bs[lc + 5][lr] = b1.y;
        Bs[lc + 6][lr] = b1.z; Bs[lc + 7][lr] = b1.w;
        __syncthreads();
        #pragma unroll
        for (int kk = 0; kk < BK; kk++) {
            float a[8], b[8];
            *(float4*)&a[0] = *(const float4*)&As[kk][ty * 8];
            *(float4*)&a[4] = *(const float4*)&As[kk][ty * 8 + 4];
            *(float4*)&b[0] = *(const float4*)&Bs[kk][tx * 8];
            *(float4*)&b[4] = *(const float4*)&Bs[kk][tx * 8 + 4];
            #pragma unroll
            for (int i = 0; i < 8; i++)
                #pragma unroll
                for (int j = 0; j < 8; j++)
                    acc[i][j] = fmaf(a[i], b[j], acc[i][j]);
        }
    }

    const float bw = *bwp;
    const float inv0 = 1.0f / bw;
    const float invb[5] = {inv0, inv0 * 0.5f, inv0 * 0.25f, inv0 * 0.125f, inv0 * 0.0625f};
    constexpr float INV_T = 1.0f / 0.35f;

    float sqR[8], sqC[8];
    int labR[8], labC[8];
    #pragma unroll
    for (int i = 0; i < 8; i++) {
        int r = rowBase + ty * 8 + i;
        sqR[i] = sq[r]; labR[i] = lab[r];
    }
    #pragma unroll
    for (int j = 0; j < 8; j++) {
        int c = colBase + tx * 8 + j;
        sqC[j] = sq[c]; labC[j] = lab[c];
    }

    #pragma unroll
    for (int i = 0; i < 8; i++) {
        int r = rowBase + ty * 8 + i;
        float dAcc = 0.f, sAcc = 0.f;
        #pragma unroll
        for (int j = 0; j < 8; j++) {
            int c = colBase + tx * 8 + j;
            float L2 = fmaxf(sqR[i] + sqC[j] - 2.0f * acc[i][j], 0.0f);
            float kern = 0.f;
            #pragma unroll
            for (int m = 0; m < 5; m++) kern += __expf(-L2 * invb[m]);
            float logit = (kern - 5.0f) * INV_T;
            if (r != c) {
                dAcc += __expf(logit);
                if (labR[i] == labC[j]) sAcc += logit;
            }
        }
        #pragma unroll
        for (int m = 8; m; m >>= 1) {
            dAcc += __shfl_xor(dAcc, m);
            sAcc += __shfl_xor(sAcc, m);
        }
        if (tx == 0) {
            atomicAdd(&denom[r], dAcc);
            atomicAdd(&Ssum[r], sAcc);
        }
    }
}

__global__ __launch_bounds__(1024) void finalize_old_kernel(const float* __restrict__ denom,
                                                            const float* __restrict__ Ssum,
                                                            const int* __restrict__ lab,
                                                            const int* __restrict__ cnt,
                                                            float* __restrict__ out) {
    int tid = threadIdx.x;
    float lsum = 0.f, vcnt = 0.f;
    for (int r = tid; r < N; r += 1024) {
        int P = cnt[lab[r]] - 1;
        if (P > 0) {
            float fl = (float)P;
            float mean = (Ssum[r] - fl * logf(denom[r])) / fl;
            lsum -= mean;
            vcnt += 1.f;
        }
    }
    __shared__ float s1[16], s2[16];
    int lane = tid & 63, wv = tid >> 6;
    #pragma unroll
    for (int m = 32; m; m >>= 1) {
        lsum += __shfl_xor(lsum, m);
        vcnt += __shfl_xor(vcnt, m);
    }
    if (lane == 0) { s1[wv] = lsum; s2[wv] = vcnt; }
    __syncthreads();
    if (wv == 0) {
        float a = (lane < 16) ? s1[lane] : 0.f;
        float b = (lane < 16) ? s2[lane] : 0.f;
        #pragma unroll
        for (int m = 8; m; m >>= 1) {
            a += __shfl_xor(a, m);
            b += __shfl_xor(b, m);
        }
        if (lane == 0) out[0] = a / fmaxf(b, 1.0f);
    }
}

extern "C" void kernel_launch(void* const* d_in, const int* in_sizes, int n_in,
                              void* d_out, int out_size, void* d_ws, size_t ws_size,
                              hipStream_t stream) {
    const float* X = (const float*)d_in[0];
    const int* lab = (const int*)d_in[1];
    float* ws = (float*)d_ws;

    if (ws_size >= WS_NEED) {
        u16* hi = (u16*)ws;
        float* sqh = ws + OFF_SQH;
        float* denP = ws + OFF_DENP;
        float* SP = ws + OFF_SP;
        float* colsum = ws + OFF_COLSUM;
        float* sumsq = ws + OFF_SUMSQ;
        float* lsSum = ws + OFF_LS;
        float* vsSum = ws + OFF_VS;
        int* ticket = (int*)(ws + OFF_TK);

        hipMemsetAsync(colsum, 0, ZERO_FLOATS * sizeof(float), stream);
        prep_kernel<<<256, 256, 0, stream>>>(X, hi, sqh, colsum, sumsq);
        gemm_mfma_kernel<<<(32 * 33) / 2, 256, 0, stream>>>(hi, lab, sqh, colsum, sumsq,
                                                            denP, SP);
        fin_kernel<<<16, 256, 0, stream>>>(denP, SP, lab, lsSum, vsSum, ticket,
                                           (float*)d_out);
    } else {
        float* sq = ws;
        float* denom = ws + 4096;
        float* Ssum = ws + 8192;
        float* colsum = ws + 12288;
        float* sumsq = ws + 12800;
        float* bw = ws + 12801;
        int* cnt = (int*)(ws + 12802);

        hipMemsetAsync(d_ws, 0, WS_FLOATS_OLD * sizeof(float), stream);
        rowsq_kernel<<<N / 4, 256, 0, stream>>>(X, sq, sumsq);
        colsum_kernel<<<N / 64, 256, 0, stream>>>(X, colsum);
        hist_kernel<<<(N + 255) / 256, 256, 0, stream>>>(lab, cnt);
        bw_kernel<<<1, 64, 0, stream>>>(colsum, sumsq, bw);
        gemm_fused_kernel<<<(N / BM) * (N / BN), 256, 0, stream>>>(X, lab, sq, bw, denom, Ssum);
        finalize_old_kernel<<<1, 1024, 0, stream>>>(denom, Ssum, lab, cnt, (float*)d_out);
    }
}

// Round 10
// 65.692 us; speedup vs baseline: 1.1270x; 1.1270x over previous
//
#include <hip/hip_runtime.h>
#include <math.h>

#define N 4096
#define D 512
#define NCLASS 31

typedef unsigned short u16;
typedef unsigned int u32;
typedef short bf16x8 __attribute__((ext_vector_type(8)));
typedef float f32x4 __attribute__((ext_vector_type(4)));

__device__ __forceinline__ u32 f2bf(float x) {
    u32 u = __float_as_uint(x);
    return (u + 0x7FFFu + ((u >> 16) & 1u)) >> 16;  // RNE bf16 (no inf/nan in data)
}
__device__ __forceinline__ float bf2f(u32 h) {
    return __uint_as_float(h << 16);
}

__device__ __forceinline__ void gll16(const void* g, void* l) {
    __builtin_amdgcn_global_load_lds(
        (const __attribute__((address_space(1))) u32*)g,
        (__attribute__((address_space(3))) u32*)l, 16, 0, 0);
}

// ---------------- ws layout (float units) ----------------
constexpr size_t HI_FLOATS  = (size_t)N * D / 2;        // bf16 copy of X
constexpr size_t OFF_SQH    = HI_FLOATS;                // N
constexpr size_t OFF_DENP   = OFF_SQH + N;              // 16*N slabs
constexpr size_t OFF_SP     = OFF_DENP + 16 * (size_t)N;// 16*N slabs
constexpr size_t OFF_COLSUM = OFF_SP + 16 * (size_t)N;  // 512
constexpr size_t OFF_SUMSQ  = OFF_COLSUM + 512;         // 1
constexpr size_t OFF_LS     = OFF_SUMSQ + 1;            // 1 loss-sum
constexpr size_t OFF_VS     = OFF_LS + 1;               // 1 valid-sum
constexpr size_t OFF_TK     = OFF_VS + 1;               // 1 ticket (int)
constexpr size_t ZERO_FLOATS = 512 + 4;                 // colsum..ticket
constexpr size_t WS_NEED    = (OFF_TK + 64) * 4;        // ~4.8 MB

// ============ prep: fp32->bf16 + colsum/sumsq atomics + rowsq ============
__global__ __launch_bounds__(256) void prep_kernel(const float* __restrict__ X,
                                                   u16* __restrict__ hi,
                                                   float* __restrict__ sqh,
                                                   float* __restrict__ colsum,
                                                   float* __restrict__ sumsq) {
    const int t = threadIdx.x;
    const int r0 = blockIdx.x * 16;
    float cs0 = 0.f, cs1 = 0.f, ss = 0.f;
    #pragma unroll 4
    for (int r = r0; r < r0 + 16; r++) {
        float2 v = *(const float2*)(X + (size_t)r * D + t * 2);
        u32 h0 = f2bf(v.x), h1 = f2bf(v.y);
        *(u32*)(hi + (size_t)r * D + t * 2) = h0 | (h1 << 16);
        float q0 = bf2f(h0), q1 = bf2f(h1);
        cs0 += q0; cs1 += q1;
        ss += q0 * q0 + q1 * q1;
    }
    atomicAdd(&colsum[t * 2], cs0);
    atomicAdd(&colsum[t * 2 + 1], cs1);
    __shared__ float red[4];
    const int ln = t & 63, wv = t >> 6;
    #pragma unroll
    for (int m = 32; m; m >>= 1) ss += __shfl_xor(ss, m);
    if (ln == 0) red[wv] = ss;
    __syncthreads();
    if (t == 0) atomicAdd(sumsq, red[0] + red[1] + red[2] + red[3]);
    #pragma unroll
    for (int i = 0; i < 4; i++) {
        int r = r0 + wv * 4 + i;
        bf16x8 v = *(const bf16x8*)(hi + (size_t)r * D + ln * 8);
        float s = 0.f;
        #pragma unroll
        for (int j = 0; j < 8; j++) { float f = bf2f((u16)(unsigned short)v[j]); s += f * f; }
        #pragma unroll
        for (int m = 32; m; m >>= 1) s += __shfl_xor(s, m);
        if (ln == 0) sqh[r] = s;
    }
}

// ============ fused MFMA Gram + RBF + contrastive stats, 256^2 8-wave ============
// Full N x N (no symmetry): grid 16x16 = 256 blocks = EXACTLY 1/CU (128KB LDS),
// zero dispatch tail. 512 threads = 8 waves (2 row-halves x 4 col-quarters),
// per-wave output 128x64 -> per K-tile(64) per CU: 512 MFMA ~= 2.5k cycles of
// matrix-pipe work (vs ~160 at the 128^2/4-wave structure) — enough to cover
// global-load latency with 2 waves/SIMD. Counted vmcnt(8), never 0 mid-loop.
// LDS [256][64] u16 row-major (row=128B): staging dest byte = tid*16 (linear,
// gll16-compatible); global chunk pre-swizzled (tid&7)^((tid>>3)&7) so each
// 8-lane octet covers one full 128B line (coalesced, no half-line refetch).
// Fragment read chunk phys = (s*4+(l>>4))^(l&7): each octet tiles all 32 banks.
__global__ __launch_bounds__(512, 2) void gemm_mfma_kernel(const u16* __restrict__ hi,
                                                           const int* __restrict__ lab,
                                                           const float* __restrict__ sqh,
                                                           const float* __restrict__ colsum,
                                                           const float* __restrict__ sumsq,
                                                           float* __restrict__ denP,
                                                           float* __restrict__ SP) {
    __shared__ u16 As[2][256 * 64];
    __shared__ u16 Bs[2][256 * 64];
    __shared__ float bwS;
    const int tid = threadIdx.x;
    const int w = tid >> 6, l = tid & 63;
    const int wr = w >> 2, wc = w & 3;

    // XCD swizzle (256 = 8*32, bijective): consecutive in-XCD blocks share by
    const int bid = blockIdx.x;
    const int b = (bid & 7) * 32 + (bid >> 3);
    const int bx = b & 15, by = b >> 4;
    const int rowBase = by * 256, colBase = bx * 256;

    // staging: phys chunk tid&7 of row tid>>3 (+i*64); global logical chunk XOR'd
    const u16* pA = hi + (size_t)(rowBase + (tid >> 3)) * D + (((tid & 7) ^ ((tid >> 3) & 7)) * 8);
    const u16* pB = hi + (size_t)(colBase + (tid >> 3)) * D + (((tid & 7) ^ ((tid >> 3) & 7)) * 8);

#define STAGE(BUF, KT) {                                                        \
    _Pragma("unroll")                                                           \
    for (int i = 0; i < 4; i++)                                                 \
        gll16(pA + (size_t)(i * 64) * D + (KT) * 64, &As[BUF][i * 4096 + tid * 8]); \
    _Pragma("unroll")                                                           \
    for (int i = 0; i < 4; i++)                                                 \
        gll16(pB + (size_t)(i * 64) * D + (KT) * 64, &Bs[BUF][i * 4096 + tid * 8]); }

    STAGE(0, 0)

    // bandwidth preamble (wave 0; 2KB; overlaps stage-0 flight)
    if (tid < 64) {
        float s = 0.f;
        for (int k = tid; k < D; k += 64) { float v = colsum[k]; s += v * v; }
        #pragma unroll
        for (int m = 32; m; m >>= 1) s += __shfl_xor(s, m);
        if (tid == 0) {
            double total = 2.0 * (double)N * (double)(*sumsq) - 2.0 * (double)s;
            bwS = (float)(total / ((double)N * (double)N - (double)N) * 0.25);
        }
    }
    __syncthreads();  // publishes bwS; drains stage-0 + preamble (one-time)

    f32x4 zero = {0.f, 0.f, 0.f, 0.f};
    f32x4 acc[8][4];
    #pragma unroll
    for (int i = 0; i < 8; i++)
        #pragma unroll
        for (int j = 0; j < 4; j++) acc[i][j] = zero;

#define KSTEP(T, CNT) {                                                         \
    if ((T) < 7) STAGE(((T) + 1) & 1, (T) + 1)                                  \
    asm volatile("s_waitcnt vmcnt(" CNT ")\n\ts_barrier" ::: "memory");         \
    _Pragma("unroll")                                                           \
    for (int s = 0; s < 2; s++) {                                               \
        bf16x8 af[8], bfr[4];                                                   \
        const int pc = ((s * 4 + (l >> 4)) ^ (l & 7)) * 8;                      \
        _Pragma("unroll")                                                       \
        for (int m = 0; m < 8; m++)                                             \
            af[m] = *(const bf16x8*)&As[(T) & 1][(wr * 128 + m * 16 + (l & 15)) * 64 + pc]; \
        _Pragma("unroll")                                                       \
        for (int n = 0; n < 4; n++)                                             \
            bfr[n] = *(const bf16x8*)&Bs[(T) & 1][(wc * 64 + n * 16 + (l & 15)) * 64 + pc]; \
        _Pragma("unroll")                                                       \
        for (int m = 0; m < 8; m++)                                             \
            _Pragma("unroll")                                                   \
            for (int n = 0; n < 4; n++)                                         \
                acc[m][n] = __builtin_amdgcn_mfma_f32_16x16x32_bf16(            \
                    af[m], bfr[n], acc[m][n], 0, 0, 0);                         \
    }                                                                           \
    asm volatile("s_barrier" ::: "memory"); }

    KSTEP(0, "8") KSTEP(1, "8") KSTEP(2, "8") KSTEP(3, "8")
    KSTEP(4, "8") KSTEP(5, "8") KSTEP(6, "8") KSTEP(7, "0")
#undef KSTEP
#undef STAGE

    // ---- epilogue: L2 -> 5-kernel sum via u^{1,2,4,8,16} -> row partials ----
    const float bw = bwS;
    const float c4 = 1.0f / (16.0f * bw);
    constexpr float INV_T = 1.0f / 0.35f;  // 1/(TEMPERATURE*KERNEL_NUM)

    const int col0 = colBase + wc * 64 + (l & 15);
    float sqC[4]; int labC[4];
    #pragma unroll
    for (int n = 0; n < 4; n++) { sqC[n] = sqh[col0 + n * 16]; labC[n] = lab[col0 + n * 16]; }
    const int rbase = rowBase + wr * 128 + (l >> 4) * 4;

    // LDS scratch over As[0]: fD/fS[4 wc][256 rows]
    float* fD = (float*)&As[0][0];
    float* fS = fD + 1024;

    #pragma unroll
    for (int m = 0; m < 8; m++) {
        #pragma unroll
        for (int rg = 0; rg < 4; rg++) {
            const int r = rbase + m * 16 + rg;
            const float sqR = sqh[r];
            const int labR = lab[r];
            float dA = 0.f, sA2 = 0.f;
            #pragma unroll
            for (int n = 0; n < 4; n++) {
                float gv = acc[m][n][rg];
                float L2 = fmaxf(sqR + sqC[n] - 2.0f * gv, 0.0f);
                float u = __expf(-L2 * c4);
                float u2 = u * u, u4 = u2 * u2, u8 = u4 * u4, u16v = u8 * u8;
                float k5 = ((((u + u2) + u4) + u8) + u16v) - 5.0f;  // kern-5 (diag->0 exact)
                dA += __expf(k5 * INV_T);   // diag contributes exactly 1.0, removed in fin
                if (labR == labC[n]) sA2 += k5;
            }
            #pragma unroll
            for (int mm = 1; mm <= 8; mm <<= 1) {
                dA += __shfl_xor(dA, mm);
                sA2 += __shfl_xor(sA2, mm);
            }
            if ((l & 15) == 0) {
                int rloc = wr * 128 + m * 16 + (l >> 4) * 4 + rg;  // 0..255
                fD[wc * 256 + rloc] = dA;
                fS[wc * 256 + rloc] = sA2;
            }
        }
    }
    __syncthreads();
    if (tid < 256) {
        float den = fD[tid] + fD[256 + tid] + fD[512 + tid] + fD[768 + tid];
        float ssv = fS[tid] + fS[256 + tid] + fS[512 + tid] + fS[768 + tid];
        denP[(size_t)bx * N + rowBase + tid] = den;
        SP[(size_t)bx * N + rowBase + tid]   = ssv;
    }
}

// ============ finalize (fused): per-row loss -> block sums -> ticket ============
__global__ __launch_bounds__(256) void fin_kernel(const float* __restrict__ denP,
                                                  const float* __restrict__ SP,
                                                  const int* __restrict__ lab,
                                                  float* __restrict__ lsSum,
                                                  float* __restrict__ vsSum,
                                                  int* __restrict__ ticket,
                                                  float* __restrict__ out) {
    __shared__ int h[NCLASS];
    const int tid = threadIdx.x;
    if (tid < NCLASS) h[tid] = 0;
    __syncthreads();
    for (int i = tid; i < N; i += 256) atomicAdd(&h[lab[i]], 1);  // LDS atomics
    __syncthreads();
    const int r = blockIdx.x * 256 + tid;
    float dsum = -1.0f, ssum = 0.0f;  // -1: exact diagonal exp-term removal
    #pragma unroll 8
    for (int k = 0; k < 16; k++) {
        dsum += denP[(size_t)k * N + r];
        ssum += SP[(size_t)k * N + r];
    }
    constexpr float INV_T = 1.0f / 0.35f;
    int P = h[lab[r]] - 1;
    float loss = 0.f, val = 0.f;
    if (P > 0) {
        float fl = (float)P;
        loss = -(ssum * INV_T - fl * logf(dsum)) / fl;
        val = 1.f;
    }
    __shared__ float s1[4], s2[4];
    const int ln = tid & 63, wv = tid >> 6;
    #pragma unroll
    for (int m = 32; m; m >>= 1) {
        loss += __shfl_xor(loss, m);
        val  += __shfl_xor(val, m);
    }
    if (ln == 0) { s1[wv] = loss; s2[wv] = val; }
    __syncthreads();
    if (tid == 0) {
        atomicAdd(lsSum, s1[0] + s1[1] + s1[2] + s1[3]);
        atomicAdd(vsSum, s2[0] + s2[1] + s2[2] + s2[3]);
        __threadfence();
        if (atomicAdd(ticket, 1) == (int)gridDim.x - 1) {
            float a = atomicAdd(lsSum, 0.0f);
            float v = atomicAdd(vsSum, 0.0f);
            out[0] = a / fmaxf(v, 1.0f);
        }
    }
}

// ======================================================================
// ================= fallback fp32 path (round-1, known-good) ===========
// ======================================================================
constexpr int WS_FLOATS_OLD = 12802 + 32;

__global__ __launch_bounds__(256) void rowsq_kernel(const float* __restrict__ X,
                                                    float* __restrict__ sq,
                                                    float* __restrict__ sumsq) {
    int wave = threadIdx.x >> 6;
    int lane = threadIdx.x & 63;
    int row = blockIdx.x * 4 + wave;
    const float4* p = (const float4*)(X + (size_t)row * D);
    float4 v0 = p[lane * 2];
    float4 v1 = p[lane * 2 + 1];
    float s = v0.x * v0.x + v0.y * v0.y + v0.z * v0.z + v0.w * v0.w
            + v1.x * v1.x + v1.y * v1.y + v1.z * v1.z + v1.w * v1.w;
    #pragma unroll
    for (int m = 32; m; m >>= 1) s += __shfl_xor(s, m);
    if (lane == 0) { sq[row] = s; atomicAdd(sumsq, s); }
}

__global__ __launch_bounds__(256) void colsum_kernel(const float* __restrict__ X,
                                                     float* __restrict__ colsum) {
    int c0 = threadIdx.x;
    int c1 = threadIdx.x + 256;
    int r0 = blockIdx.x * 64;
    float s0 = 0.f, s1 = 0.f;
    for (int r = r0; r < r0 + 64; r++) {
        s0 += X[(size_t)r * D + c0];
        s1 += X[(size_t)r * D + c1];
    }
    atomicAdd(&colsum[c0], s0);
    atomicAdd(&colsum[c1], s1);
}

__global__ __launch_bounds__(256) void hist_kernel(const int* __restrict__ lab,
                                                   int* __restrict__ cnt) {
    int i = blockIdx.x * 256 + threadIdx.x;
    if (i < N) atomicAdd(&cnt[lab[i]], 1);
}

__global__ __launch_bounds__(64) void bw_kernel(const float* __restrict__ colsum,
                                                const float* __restrict__ sumsq,
                                                float* __restrict__ bw) {
    int lane = threadIdx.x;
    float s = 0.f;
    for (int k = lane; k < D; k += 64) { float v = colsum[k]; s += v * v; }
    #pragma unroll
    for (int m = 32; m; m >>= 1) s += __shfl_xor(s, m);
    if (lane == 0) {
        double total = 2.0 * (double)N * (double)(*sumsq) - 2.0 * (double)s;
        double b = total / ((double)N * (double)N - (double)N);
        *bw = (float)(b / 4.0);
    }
}

constexpr int BM = 128, BN = 128, BK = 16;

__global__ __launch_bounds__(256) void gemm_fused_kernel(const float* __restrict__ X,
                                                         const int* __restrict__ lab,
                                                         const float* __restrict__ sq,
                                                         const float* __restrict__ bwp,
                                                         float* __restrict__ denom,
                                                         float* __restrict__ Ssum) {
    __shared__ float As[BK][BM];
    __shared__ float Bs[BK][BN];
    const int tid = threadIdx.x;
    const int nbx = N / BN;
    const int bx = blockIdx.x % nbx;
    const int by = blockIdx.x / nbx;
    const int rowBase = by * BM, colBase = bx * BN;
    const int lr = tid >> 1;
    const int lc = (tid & 1) * 8;
    const float* Ap = X + (size_t)(rowBase + lr) * D + lc;
    const float* Bp = X + (size_t)(colBase + lr) * D + lc;
    const int ty = tid >> 4, tx = tid & 15;

    float acc[8][8];
    #pragma unroll
    for (int i = 0; i < 8; i++)
        #pragma unroll
        for (int j = 0; j < 8; j++) acc[i][j] = 0.f;

    for (int k0 = 0; k0 < D; k0 += BK) {
        float4 a0 = *(const float4*)(Ap + k0);
        float4 a1 = *(const float4*)(Ap + k0 + 4);
        float4 b0 = *(const float4*)(Bp + k0);
        float4 b1 = *(const float4*)(Bp + k0 + 4);
        __syncthreads();
        As[lc + 0][lr] = a0.x; As[lc + 1][lr] = a0.y;
        As[lc + 2][lr] = a0.z; As[lc + 3][lr] = a0.w;
        As[lc + 4][lr] = a1.x; As[lc + 5][lr] = a1.y;
        As[lc + 6][lr] = a1.z; As[lc + 7][lr] = a1.w;
        Bs[lc + 0][lr] = b0.x; Bs[lc + 1][lr] = b0.y;
        Bs[lc + 2][lr] = b0.z; Bs[lc + 3][lr] = b0.w;
        Bs[lc + 4][lr] = b1.x; Bs[lc + 5][lr] = b1.y;
        Bs[lc + 6][lr] = b1.z; Bs[lc + 7][lr] = b1.w;
        __syncthreads();
        #pragma unroll
        for (int kk = 0; kk < BK; kk++) {
            float a[8], b[8];
            *(float4*)&a[0] = *(const float4*)&As[kk][ty * 8];
            *(float4*)&a[4] = *(const float4*)&As[kk][ty * 8 + 4];
            *(float4*)&b[0] = *(const float4*)&Bs[kk][tx * 8];
            *(float4*)&b[4] = *(const float4*)&Bs[kk][tx * 8 + 4];
            #pragma unroll
            for (int i = 0; i < 8; i++)
                #pragma unroll
                for (int j = 0; j < 8; j++)
                    acc[i][j] = fmaf(a[i], b[j], acc[i][j]);
        }
    }

    const float bw = *bwp;
    const float inv0 = 1.0f / bw;
    const float invb[5] = {inv0, inv0 * 0.5f, inv0 * 0.25f, inv0 * 0.125f, inv0 * 0.0625f};
    constexpr float INV_T = 1.0f / 0.35f;

    float sqR[8], sqC[8];
    int labR[8], labC[8];
    #pragma unroll
    for (int i = 0; i < 8; i++) {
        int r = rowBase + ty * 8 + i;
        sqR[i] = sq[r]; labR[i] = lab[r];
    }
    #pragma unroll
    for (int j = 0; j < 8; j++) {
        int c = colBase + tx * 8 + j;
        sqC[j] = sq[c]; labC[j] = lab[c];
    }

    #pragma unroll
    for (int i = 0; i < 8; i++) {
        int r = rowBase + ty * 8 + i;
        float dAcc = 0.f, sAcc = 0.f;
        #pragma unroll
        for (int j = 0; j < 8; j++) {
            int c = colBase + tx * 8 + j;
            float L2 = fmaxf(sqR[i] + sqC[j] - 2.0f * acc[i][j], 0.0f);
            float kern = 0.f;
            #pragma unroll
            for (int m = 0; m < 5; m++) kern += __expf(-L2 * invb[m]);
            float logit = (kern - 5.0f) * INV_T;
            if (r != c) {
                dAcc += __expf(logit);
                if (labR[i] == labC[j]) sAcc += logit;
            }
        }
        #pragma unroll
        for (int m = 8; m; m >>= 1) {
            dAcc += __shfl_xor(dAcc, m);
            sAcc += __shfl_xor(sAcc, m);
        }
        if (tx == 0) {
            atomicAdd(&denom[r], dAcc);
            atomicAdd(&Ssum[r], sAcc);
        }
    }
}

__global__ __launch_bounds__(1024) void finalize_old_kernel(const float* __restrict__ denom,
                                                            const float* __restrict__ Ssum,
                                                            const int* __restrict__ lab,
                                                            const int* __restrict__ cnt,
                                                            float* __restrict__ out) {
    int tid = threadIdx.x;
    float lsum = 0.f, vcnt = 0.f;
    for (int r = tid; r < N; r += 1024) {
        int P = cnt[lab[r]] - 1;
        if (P > 0) {
            float fl = (float)P;
            float mean = (Ssum[r] - fl * logf(denom[r])) / fl;
            lsum -= mean;
            vcnt += 1.f;
        }
    }
    __shared__ float s1[16], s2[16];
    int lane = tid & 63, wv = tid >> 6;
    #pragma unroll
    for (int m = 32; m; m >>= 1) {
        lsum += __shfl_xor(lsum, m);
        vcnt += __shfl_xor(vcnt, m);
    }
    if (lane == 0) { s1[wv] = lsum; s2[wv] = vcnt; }
    __syncthreads();
    if (wv == 0) {
        float a = (lane < 16) ? s1[lane] : 0.f;
        float b = (lane < 16) ? s2[lane] : 0.f;
        #pragma unroll
        for (int m = 8; m; m >>= 1) {
            a += __shfl_xor(a, m);
            b += __shfl_xor(b, m);
        }
        if (lane == 0) out[0] = a / fmaxf(b, 1.0f);
    }
}

extern "C" void kernel_launch(void* const* d_in, const int* in_sizes, int n_in,
                              void* d_out, int out_size, void* d_ws, size_t ws_size,
                              hipStream_t stream) {
    const float* X = (const float*)d_in[0];
    const int* lab = (const int*)d_in[1];
    float* ws = (float*)d_ws;

    if (ws_size >= WS_NEED) {
        u16* hi = (u16*)ws;
        float* sqh = ws + OFF_SQH;
        float* denP = ws + OFF_DENP;
        float* SP = ws + OFF_SP;
        float* colsum = ws + OFF_COLSUM;
        float* sumsq = ws + OFF_SUMSQ;
        float* lsSum = ws + OFF_LS;
        float* vsSum = ws + OFF_VS;
        int* ticket = (int*)(ws + OFF_TK);

        hipMemsetAsync(colsum, 0, ZERO_FLOATS * sizeof(float), stream);
        prep_kernel<<<256, 256, 0, stream>>>(X, hi, sqh, colsum, sumsq);
        gemm_mfma_kernel<<<256, 512, 0, stream>>>(hi, lab, sqh, colsum, sumsq, denP, SP);
        fin_kernel<<<16, 256, 0, stream>>>(denP, SP, lab, lsSum, vsSum, ticket,
                                           (float*)d_out);
    } else {
        float* sq = ws;
        float* denom = ws + 4096;
        float* Ssum = ws + 8192;
        float* colsum = ws + 12288;
        float* sumsq = ws + 12800;
        float* bw = ws + 12801;
        int* cnt = (int*)(ws + 12802);

        hipMemsetAsync(d_ws, 0, WS_FLOATS_OLD * sizeof(float), stream);
        rowsq_kernel<<<N / 4, 256, 0, stream>>>(X, sq, sumsq);
        colsum_kernel<<<N / 64, 256, 0, stream>>>(X, colsum);
        hist_kernel<<<(N + 255) / 256, 256, 0, stream>>>(lab, cnt);
        bw_kernel<<<1, 64, 0, stream>>>(colsum, sumsq, bw);
        gemm_fused_kernel<<<(N / BM) * (N / BN), 256, 0, stream>>>(X, lab, sq, bw, denom, Ssum);
        finalize_old_kernel<<<1, 1024, 0, stream>>>(denom, Ssum, lab, cnt, (float*)d_out);
    }
}